// Round 9
// baseline (912.929 us; speedup 1.0000x reference)
//
#include <hip/hip_runtime.h>
#include <stdint.h>

#define N_TOKENS  8192
#define D_MODEL   1024
#define D_FF      4096
#define TOP_K     2
#define N_EXPERTS 8
#define TOTAL_SLOTS (N_TOKENS * TOP_K)   // 16384
#define CAP       4096                    // 2.0 * 16384 / 8
#define ROWS_PAD  (TOTAL_SLOTS + 128)     // pad so tile staging never reads OOB

typedef unsigned short u16;
typedef __attribute__((ext_vector_type(4))) float f32x4;
typedef __attribute__((ext_vector_type(8))) short bf16x8;

__device__ __forceinline__ float bf2f(u16 u) {
  union { unsigned int i; float f; } v; v.i = ((unsigned int)u) << 16; return v.f;
}
__device__ __forceinline__ u16 f2bf(float f) {
  union { float f; unsigned int i; } v; v.f = f;
  unsigned int u = v.i;
  return (u16)((u + 0x7FFFu + ((u >> 16) & 1u)) >> 16);  // RN-even
}

// async global->LDS, 16B per lane; LDS dest is wave-uniform base + lane*16
__device__ __forceinline__ void gld_lds16(const void* g, void* l) {
  __builtin_amdgcn_global_load_lds(
      (const __attribute__((address_space(1))) unsigned int*)g,
      (__attribute__((address_space(3))) unsigned int*)l,
      16, 0, 0);
}

// ---------------------------------------------------------------------------
// Routing v2: deterministic stable counting sort, latency-optimized.
// (R7-verbatim, known good.)
// ---------------------------------------------------------------------------
#define RT_THREADS 1024
#define RT_ROUNDS  (TOTAL_SLOTS / RT_THREADS)   // 16
#define RT_WAVES   (RT_THREADS / 64)            // 16

__global__ __launch_bounds__(RT_THREADS) void k_route(const int* __restrict__ eidx,
                                                      int* __restrict__ info,
                                                      int* __restrict__ row_of_slot,
                                                      int* __restrict__ tok_of_row) {
  __shared__ int s_wcnt[RT_ROUNDS][RT_WAVES][N_EXPERTS];   // 8 KB
  __shared__ int s_pbase[RT_ROUNDS][RT_WAVES][N_EXPERTS];  // 8 KB
  __shared__ int s_start[N_EXPERTS];
  const int t = threadIdx.x, lane = t & 63, w = t >> 6;

  int e[RT_ROUNDS];
  #pragma unroll
  for (int c = 0; c < RT_ROUNDS; ++c) e[c] = eidx[c * RT_THREADS + t];

  unsigned long long mym[RT_ROUNDS];
  #pragma unroll
  for (int c = 0; c < RT_ROUNDS; ++c) {
    unsigned long long mm = 0;
    #pragma unroll
    for (int ee = 0; ee < N_EXPERTS; ++ee) {
      unsigned long long m = __ballot(e[c] == ee);
      if (e[c] == ee) mm = m;
      if (lane == ee) s_wcnt[c][w][ee] = __popcll(m);   // lanes 0..7 store
    }
    mym[c] = mm;
  }
  __syncthreads();

  if (t < N_EXPERTS) {   // exclusive prefix over (round, wave) per expert
    int tot = 0;
    for (int c = 0; c < RT_ROUNDS; ++c)
      for (int ww = 0; ww < RT_WAVES; ++ww) {
        s_pbase[c][ww][t] = tot;
        tot += s_wcnt[c][ww][t];
      }
    s_start[t] = tot;   // expert totals (temporarily)
  }
  __syncthreads();
  if (t == 0) {
    int off = 0;
    for (int ee = 0; ee < N_EXPERTS; ++ee) {
      int tot = s_start[ee];
      int placed = tot < CAP ? tot : CAP;
      info[ee] = placed;
      info[N_EXPERTS + ee] = off;
      s_start[ee] = off;   // now = segment start
      off += placed;
    }
    info[2 * N_EXPERTS] = off;
  }
  __syncthreads();

  #pragma unroll
  for (int c = 0; c < RT_ROUNDS; ++c) {
    const int s = c * RT_THREADS + t;
    const int rank = __popcll(mym[c] & ((1ULL << lane) - 1ULL));
    const int pos = s_pbase[c][w][e[c]] + rank;
    const int row = (pos < CAP) ? (s_start[e[c]] + pos) : -1;
    row_of_slot[s] = row;
    if (row >= 0) tok_of_row[row] = s >> 1;   // token = slot / TOP_K
  }
}

// ---------------------------------------------------------------------------
// Fused per-expert transpose + fp32->bf16 for all three weights in ONE launch.
// (R7-verbatim, known good; runs at the HBM roofline ~6.3 TB/s.)
// ---------------------------------------------------------------------------
__global__ __launch_bounds__(256) void k_transpose_all(const float* __restrict__ w1,
                                                       const float* __restrict__ w2,
                                                       const float* __restrict__ w3,
                                                       u16* __restrict__ W1t,
                                                       u16* __restrict__ W2t,
                                                       u16* __restrict__ W3t) {
  __shared__ float tile[64][65];
  const int z = blockIdx.z;
  const int e = z & 7, which = z >> 3;
  const float* in;
  u16* out;
  int R, C, c0, r0;
  if (which == 0)      { in = w1; out = W1t; R = D_MODEL; C = D_FF; }
  else if (which == 1) { in = w2; out = W2t; R = D_MODEL; C = D_FF; }
  else                 { in = w3; out = W3t; R = D_FF;    C = D_MODEL; }
  if (which == 2) { c0 = blockIdx.y * 64; r0 = blockIdx.x * 64; }
  else            { c0 = blockIdx.x * 64; r0 = blockIdx.y * 64; }
  in  += (size_t)e * R * C;
  out += (size_t)e * R * C;
  const int tx = threadIdx.x & 15, ty = threadIdx.x >> 4;

  #pragma unroll
  for (int rr = 0; rr < 4; ++rr) {
    int r = ty + rr * 16;
    float4 v = *(const float4*)&in[(size_t)(r0 + r) * C + c0 + tx * 4];
    tile[r][tx * 4 + 0] = v.x; tile[r][tx * 4 + 1] = v.y;
    tile[r][tx * 4 + 2] = v.z; tile[r][tx * 4 + 3] = v.w;
  }
  __syncthreads();
  #pragma unroll
  for (int rr = 0; rr < 4; ++rr) {
    int oc = ty + rr * 16;
    ushort4 o;
    o.x = f2bf(tile[tx * 4 + 0][oc]);
    o.y = f2bf(tile[tx * 4 + 1][oc]);
    o.z = f2bf(tile[tx * 4 + 2][oc]);
    o.w = f2bf(tile[tx * 4 + 3][oc]);
    *(ushort4*)&out[(size_t)(c0 + oc) * R + r0 + tx * 4] = o;
  }
}

// ---------------------------------------------------------------------------
// Gather dispatched rows of x into compacted bf16 matrix Xd [ROWS_PAD][D_MODEL]
// ---------------------------------------------------------------------------
__global__ __launch_bounds__(256) void k_dispatch(const float* __restrict__ x,
                                                  const int* __restrict__ tok_of_row,
                                                  const int* __restrict__ info,
                                                  u16* __restrict__ Xd) {
  const int r = blockIdx.x;
  const int t = threadIdx.x;
  const int total = info[2 * N_EXPERTS];
  if (r >= total) {
    ushort4 z = {0, 0, 0, 0};
    *(ushort4*)&Xd[(size_t)r * D_MODEL + t * 4] = z;
    return;
  }
  int tok = tok_of_row[r];
  float4 v = *(const float4*)&x[(size_t)tok * D_MODEL + t * 4];
  ushort4 o;
  o.x = f2bf(v.x); o.y = f2bf(v.y); o.z = f2bf(v.z); o.w = f2bf(v.w);
  *(ushort4*)&Xd[(size_t)r * D_MODEL + t * 4] = o;
}

// ---------------------------------------------------------------------------
// FFN pass 1 (fused gate+value): H = silu(Xd @ w1) * (Xd @ w2), bf16 out.
// R2 body; __launch_bounds__(256, 3): LDS 48 KiB fits 3 blocks/CU (144<=160),
// VGPR 104 fits 3 waves/SIMD (312<=512) -> raise residency 2->3 blocks/CU
// (m114: cross-block wave overlap is what hides the barrier drain).
// ---------------------------------------------------------------------------
__global__ __launch_bounds__(256, 3) void k_ffn1(const u16* __restrict__ Xd,
                                                 const u16* __restrict__ W1t,
                                                 const u16* __restrict__ W2t,
                                                 u16* __restrict__ H,
                                                 const int* __restrict__ info) {
  const int e = blockIdx.z;
  const int count = info[e];
  const int row0 = blockIdx.y * 128;
  if (row0 >= count) return;
  const int start = info[N_EXPERTS + e];
  const int col0 = blockIdx.x * 128;

  __shared__ u16 lsA[128 * 64];
  __shared__ u16 lsB1[128 * 64];
  __shared__ u16 lsB2[128 * 64];

  const int t = threadIdx.x, lane = t & 63, wid = t >> 6;
  const int wr = wid >> 1, wc = wid & 1;

  const u16* gA  = Xd  + (size_t)(start + row0) * D_MODEL;
  const u16* gB1 = W1t + (size_t)e * D_FF * D_MODEL + (size_t)col0 * D_MODEL;
  const u16* gB2 = W2t + (size_t)e * D_FF * D_MODEL + (size_t)col0 * D_MODEL;

  f32x4 accG[4][4] = {};
  f32x4 accV[4][4] = {};

  const int srow = wid * 8 + (lane >> 3);                       // + i*32
  const int skk  = (((lane & 7) ^ ((lane >> 3) & 7)) * 8);
  const int rk0 = (((0 * 4 + (lane >> 4)) ^ (lane & 7)) * 8);   // kk=0
  const int rk1 = (((1 * 4 + (lane >> 4)) ^ (lane & 7)) * 8);   // kk=1

  for (int k0 = 0; k0 < D_MODEL; k0 += 64) {
    __syncthreads();
    #pragma unroll
    for (int i = 0; i < 4; ++i) {
      int r = i * 32 + srow;
      int lbase = (i * 32 + wid * 8) * 64;
      gld_lds16(gA  + (size_t)r * D_MODEL + k0 + skk, &lsA[lbase]);
      gld_lds16(gB1 + (size_t)r * D_MODEL + k0 + skk, &lsB1[lbase]);
      gld_lds16(gB2 + (size_t)r * D_MODEL + k0 + skk, &lsB2[lbase]);
    }
    __syncthreads();   // drains vmcnt -> tiles ready
    #pragma unroll
    for (int kk = 0; kk < 2; ++kk) {
      const int rk = kk ? rk1 : rk0;
      bf16x8 a[4];
      #pragma unroll
      for (int m = 0; m < 4; ++m)
        a[m] = *(const bf16x8*)&lsA[(wr * 64 + m * 16 + (lane & 15)) * 64 + rk];
      #pragma unroll
      for (int n = 0; n < 4; ++n) {
        bf16x8 b1 = *(const bf16x8*)&lsB1[(wc * 64 + n * 16 + (lane & 15)) * 64 + rk];
        bf16x8 b2 = *(const bf16x8*)&lsB2[(wc * 64 + n * 16 + (lane & 15)) * 64 + rk];
        #pragma unroll
        for (int m = 0; m < 4; ++m) {
          accG[m][n] = __builtin_amdgcn_mfma_f32_16x16x32_bf16(a[m], b1, accG[m][n], 0, 0, 0);
          accV[m][n] = __builtin_amdgcn_mfma_f32_16x16x32_bf16(a[m], b2, accV[m][n], 0, 0, 0);
        }
      }
    }
  }

  const int rmax = count - row0;
  const size_t hbase = (size_t)(start + row0);
  #pragma unroll
  for (int m = 0; m < 4; ++m) {
    #pragma unroll
    for (int j = 0; j < 4; ++j) {
      int rit = wr * 64 + m * 16 + (lane >> 4) * 4 + j;  // D: row=(lane>>4)*4+reg
      if (rit < rmax) {
        #pragma unroll
        for (int n = 0; n < 4; ++n) {
          float g = accG[m][n][j];
          float v = accV[m][n][j];
          float h = g * v / (1.0f + __expf(-g));   // silu(g)*v
          H[(hbase + rit) * D_FF + col0 + wc * 64 + n * 16 + (lane & 15)] = f2bf(h);
        }
      }
    }
  }
}

// ---------------------------------------------------------------------------
// FFN pass 2: Y = H @ w3 (B^T layout), bf16 out. R2-verbatim (known good):
// 128x128 tile, BK=64, 4 waves, 32 KiB LDS -> ~4 blocks/CU residency.
// ---------------------------------------------------------------------------
__global__ __launch_bounds__(256) void k_ffn2(const u16* __restrict__ Hbuf,
                                              const u16* __restrict__ W3t,
                                              u16* __restrict__ Y,
                                              const int* __restrict__ info) {
  const int e = blockIdx.z;
  const int count = info[e];
  const int row0 = blockIdx.y * 128;
  if (row0 >= count) return;
  const int start = info[N_EXPERTS + e];
  const int col0 = blockIdx.x * 128;

  __shared__ u16 lsA[128 * 64];
  __shared__ u16 lsB[128 * 64];

  const int t = threadIdx.x, lane = t & 63, wid = t >> 6;
  const int wr = wid >> 1, wc = wid & 1;

  const u16* gA = Hbuf + (size_t)(start + row0) * D_FF;
  const u16* gB = W3t + (size_t)e * D_MODEL * D_FF + (size_t)col0 * D_FF;

  f32x4 acc[4][4] = {};

  const int srow = wid * 8 + (lane >> 3);
  const int skk  = (((lane & 7) ^ ((lane >> 3) & 7)) * 8);
  const int rk0 = (((0 * 4 + (lane >> 4)) ^ (lane & 7)) * 8);
  const int rk1 = (((1 * 4 + (lane >> 4)) ^ (lane & 7)) * 8);

  for (int k0 = 0; k0 < D_FF; k0 += 64) {
    __syncthreads();
    #pragma unroll
    for (int i = 0; i < 4; ++i) {
      int r = i * 32 + srow;
      int lbase = (i * 32 + wid * 8) * 64;
      gld_lds16(gA + (size_t)r * D_FF + k0 + skk, &lsA[lbase]);
      gld_lds16(gB + (size_t)r * D_FF + k0 + skk, &lsB[lbase]);
    }
    __syncthreads();
    #pragma unroll
    for (int kk = 0; kk < 2; ++kk) {
      const int rk = kk ? rk1 : rk0;
      bf16x8 a[4];
      #pragma unroll
      for (int m = 0; m < 4; ++m)
        a[m] = *(const bf16x8*)&lsA[(wr * 64 + m * 16 + (lane & 15)) * 64 + rk];
      #pragma unroll
      for (int n = 0; n < 4; ++n) {
        bf16x8 b = *(const bf16x8*)&lsB[(wc * 64 + n * 16 + (lane & 15)) * 64 + rk];
        #pragma unroll
        for (int m = 0; m < 4; ++m)
          acc[m][n] = __builtin_amdgcn_mfma_f32_16x16x32_bf16(a[m], b, acc[m][n], 0, 0, 0);
      }
    }
  }

  const int rmax = count - row0;
  const size_t ybase = (size_t)(start + row0);
  #pragma unroll
  for (int m = 0; m < 4; ++m) {
    #pragma unroll
    for (int j = 0; j < 4; ++j) {
      int rit = wr * 64 + m * 16 + (lane >> 4) * 4 + j;
      if (rit < rmax) {
        #pragma unroll
        for (int n = 0; n < 4; ++n)
          Y[(ybase + rit) * D_MODEL + col0 + wc * 64 + n * 16 + (lane & 15)] = f2bf(acc[m][n][j]);
      }
    }
  }
}

// ---------------------------------------------------------------------------
// Combine: out[t] = sum_k w[t,k] * Y[row(t,k)]   (deterministic k order)
// ---------------------------------------------------------------------------
__global__ __launch_bounds__(256) void k_combine(const u16* __restrict__ Y,
                                                 const int* __restrict__ row_of_slot,
                                                 const float* __restrict__ ew,
                                                 float* __restrict__ out) {
  const int tok = blockIdx.x;
  const int c = threadIdx.x * 4;
  const int r0 = row_of_slot[tok * 2 + 0];
  const int r1 = row_of_slot[tok * 2 + 1];
  const float w0 = ew[tok * 2 + 0];
  const float w1 = ew[tok * 2 + 1];
  float a0 = 0.f, a1 = 0.f, a2 = 0.f, a3 = 0.f;
  if (r0 >= 0) {
    ushort4 y = *(const ushort4*)&Y[(size_t)r0 * D_MODEL + c];
    a0 = w0 * bf2f(y.x); a1 = w0 * bf2f(y.y); a2 = w0 * bf2f(y.z); a3 = w0 * bf2f(y.w);
  }
  if (r1 >= 0) {
    ushort4 y = *(const ushort4*)&Y[(size_t)r1 * D_MODEL + c];
    a0 += w1 * bf2f(y.x); a1 += w1 * bf2f(y.y); a2 += w1 * bf2f(y.z); a3 += w1 * bf2f(y.w);
  }
  float4 o; o.x = a0; o.y = a1; o.z = a2; o.w = a3;
  *(float4*)&out[(size_t)tok * D_MODEL + c] = o;
}

// ---------------------------------------------------------------------------
extern "C" void kernel_launch(void* const* d_in, const int* in_sizes, int n_in,
                              void* d_out, int out_size, void* d_ws, size_t ws_size,
                              hipStream_t stream) {
  const float* x  = (const float*)d_in[0];
  const int*   ei = (const int*)d_in[1];
  const float* ew = (const float*)d_in[2];
  const float* w1 = (const float*)d_in[3];
  const float* w2 = (const float*)d_in[4];
  const float* w3 = (const float*)d_in[5];
  float* out = (float*)d_out;

  char* ws = (char*)d_ws;
  size_t off = 0;
  auto alloc = [&](size_t b) { char* p = ws + off; off += (b + 255) & ~(size_t)255; return p; };
  int* info        = (int*)alloc(256);
  int* row_of_slot = (int*)alloc(sizeof(int) * TOTAL_SLOTS);
  int* tok_of_row  = (int*)alloc(sizeof(int) * ROWS_PAD);
  u16* Xd  = (u16*)alloc((size_t)2 * ROWS_PAD * D_MODEL);
  u16* W1t = (u16*)alloc((size_t)2 * N_EXPERTS * D_FF * D_MODEL);
  u16* W2t = (u16*)alloc((size_t)2 * N_EXPERTS * D_FF * D_MODEL);
  u16* W3t = (u16*)alloc((size_t)2 * N_EXPERTS * D_FF * D_MODEL);
  u16* H   = (u16*)alloc((size_t)2 * ROWS_PAD * D_FF);
  u16* Y   = (u16*)alloc((size_t)2 * ROWS_PAD * D_MODEL);

  k_route<<<1, RT_THREADS, 0, stream>>>(ei, info, row_of_slot, tok_of_row);
  k_transpose_all<<<dim3(64, 16, 24), 256, 0, stream>>>(w1, w2, w3, W1t, W2t, W3t);
  k_dispatch<<<ROWS_PAD, 256, 0, stream>>>(x, tok_of_row, info, Xd);
  k_ffn1<<<dim3(D_FF / 128, CAP / 128, N_EXPERTS), 256, 0, stream>>>(Xd, W1t, W2t, H, info);
  k_ffn2<<<dim3(D_MODEL / 128, CAP / 128, N_EXPERTS), 256, 0, stream>>>(H, W3t, Y, info);
  k_combine<<<N_TOKENS, 256, 0, stream>>>(Y, row_of_slot, ew, out);
}

// Round 10
// 684.750 us; speedup vs baseline: 1.3332x; 1.3332x over previous
//
#include <hip/hip_runtime.h>
#include <stdint.h>

#define N_TOKENS  8192
#define D_MODEL   1024
#define D_FF      4096
#define TOP_K     2
#define N_EXPERTS 8
#define TOTAL_SLOTS (N_TOKENS * TOP_K)   // 16384
#define CAP       4096                    // 2.0 * 16384 / 8
#define ROWS_PAD  (TOTAL_SLOTS + 128)     // pad so tile staging never reads OOB

typedef unsigned short u16;
typedef __attribute__((ext_vector_type(4))) float f32x4;
typedef __attribute__((ext_vector_type(8))) short bf16x8;

__device__ __forceinline__ float bf2f(u16 u) {
  union { unsigned int i; float f; } v; v.i = ((unsigned int)u) << 16; return v.f;
}
__device__ __forceinline__ u16 f2bf(float f) {
  union { float f; unsigned int i; } v; v.f = f;
  unsigned int u = v.i;
  return (u16)((u + 0x7FFFu + ((u >> 16) & 1u)) >> 16);  // RN-even
}

// async global->LDS, 16B per lane; LDS dest is wave-uniform base + lane*16
__device__ __forceinline__ void gld_lds16(const void* g, void* l) {
  __builtin_amdgcn_global_load_lds(
      (const __attribute__((address_space(1))) unsigned int*)g,
      (__attribute__((address_space(3))) unsigned int*)l,
      16, 0, 0);
}

// ---------------------------------------------------------------------------
// Routing v2: deterministic stable counting sort, latency-optimized.
// 1 block x 1024 threads (16 waves), 16 rounds held ENTIRELY in registers.
// ---------------------------------------------------------------------------
#define RT_THREADS 1024
#define RT_ROUNDS  (TOTAL_SLOTS / RT_THREADS)   // 16
#define RT_WAVES   (RT_THREADS / 64)            // 16

__global__ __launch_bounds__(RT_THREADS) void k_route(const int* __restrict__ eidx,
                                                      int* __restrict__ info,
                                                      int* __restrict__ row_of_slot,
                                                      int* __restrict__ tok_of_row) {
  __shared__ int s_wcnt[RT_ROUNDS][RT_WAVES][N_EXPERTS];   // 8 KB
  __shared__ int s_pbase[RT_ROUNDS][RT_WAVES][N_EXPERTS];  // 8 KB
  __shared__ int s_start[N_EXPERTS];
  const int t = threadIdx.x, lane = t & 63, w = t >> 6;

  int e[RT_ROUNDS];
  #pragma unroll
  for (int c = 0; c < RT_ROUNDS; ++c) e[c] = eidx[c * RT_THREADS + t];

  unsigned long long mym[RT_ROUNDS];
  #pragma unroll
  for (int c = 0; c < RT_ROUNDS; ++c) {
    unsigned long long mm = 0;
    #pragma unroll
    for (int ee = 0; ee < N_EXPERTS; ++ee) {
      unsigned long long m = __ballot(e[c] == ee);
      if (e[c] == ee) mm = m;
      if (lane == ee) s_wcnt[c][w][ee] = __popcll(m);   // lanes 0..7 store
    }
    mym[c] = mm;
  }
  __syncthreads();

  if (t < N_EXPERTS) {   // exclusive prefix over (round, wave) per expert
    int tot = 0;
    for (int c = 0; c < RT_ROUNDS; ++c)
      for (int ww = 0; ww < RT_WAVES; ++ww) {
        s_pbase[c][ww][t] = tot;
        tot += s_wcnt[c][ww][t];
      }
    s_start[t] = tot;   // expert totals (temporarily)
  }
  __syncthreads();
  if (t == 0) {
    int off = 0;
    for (int ee = 0; ee < N_EXPERTS; ++ee) {
      int tot = s_start[ee];
      int placed = tot < CAP ? tot : CAP;
      info[ee] = placed;
      info[N_EXPERTS + ee] = off;
      s_start[ee] = off;   // now = segment start
      off += placed;
    }
    info[2 * N_EXPERTS] = off;
  }
  __syncthreads();

  #pragma unroll
  for (int c = 0; c < RT_ROUNDS; ++c) {
    const int s = c * RT_THREADS + t;
    const int rank = __popcll(mym[c] & ((1ULL << lane) - 1ULL));
    const int pos = s_pbase[c][w][e[c]] + rank;
    const int row = (pos < CAP) ? (s_start[e[c]] + pos) : -1;
    row_of_slot[s] = row;
    if (row >= 0) tok_of_row[row] = s >> 1;   // token = slot / TOP_K
  }
}

// ---------------------------------------------------------------------------
// Fused per-expert transpose + fp32->bf16 for all three weights in ONE launch.
// z = 0..23: which = z>>3 selects {w1,w2,w3}, e = z&7. HBM-roofline-bound.
// ---------------------------------------------------------------------------
__global__ __launch_bounds__(256) void k_transpose_all(const float* __restrict__ w1,
                                                       const float* __restrict__ w2,
                                                       const float* __restrict__ w3,
                                                       u16* __restrict__ W1t,
                                                       u16* __restrict__ W2t,
                                                       u16* __restrict__ W3t) {
  __shared__ float tile[64][65];
  const int z = blockIdx.z;
  const int e = z & 7, which = z >> 3;
  const float* in;
  u16* out;
  int R, C, c0, r0;
  if (which == 0)      { in = w1; out = W1t; R = D_MODEL; C = D_FF; }
  else if (which == 1) { in = w2; out = W2t; R = D_MODEL; C = D_FF; }
  else                 { in = w3; out = W3t; R = D_FF;    C = D_MODEL; }
  if (which == 2) { c0 = blockIdx.y * 64; r0 = blockIdx.x * 64; }
  else            { c0 = blockIdx.x * 64; r0 = blockIdx.y * 64; }
  in  += (size_t)e * R * C;
  out += (size_t)e * R * C;
  const int tx = threadIdx.x & 15, ty = threadIdx.x >> 4;

  #pragma unroll
  for (int rr = 0; rr < 4; ++rr) {
    int r = ty + rr * 16;
    float4 v = *(const float4*)&in[(size_t)(r0 + r) * C + c0 + tx * 4];
    tile[r][tx * 4 + 0] = v.x; tile[r][tx * 4 + 1] = v.y;
    tile[r][tx * 4 + 2] = v.z; tile[r][tx * 4 + 3] = v.w;
  }
  __syncthreads();
  #pragma unroll
  for (int rr = 0; rr < 4; ++rr) {
    int oc = ty + rr * 16;
    ushort4 o;
    o.x = f2bf(tile[tx * 4 + 0][oc]);
    o.y = f2bf(tile[tx * 4 + 1][oc]);
    o.z = f2bf(tile[tx * 4 + 2][oc]);
    o.w = f2bf(tile[tx * 4 + 3][oc]);
    *(ushort4*)&out[(size_t)(c0 + oc) * R + r0 + tx * 4] = o;
  }
}

// ---------------------------------------------------------------------------
// Gather dispatched rows of x into compacted bf16 matrix Xd [ROWS_PAD][D_MODEL]
// ---------------------------------------------------------------------------
__global__ __launch_bounds__(256) void k_dispatch(const float* __restrict__ x,
                                                  const int* __restrict__ tok_of_row,
                                                  const int* __restrict__ info,
                                                  u16* __restrict__ Xd) {
  const int r = blockIdx.x;
  const int t = threadIdx.x;
  const int total = info[2 * N_EXPERTS];
  if (r >= total) {
    ushort4 z = {0, 0, 0, 0};
    *(ushort4*)&Xd[(size_t)r * D_MODEL + t * 4] = z;
    return;
  }
  int tok = tok_of_row[r];
  float4 v = *(const float4*)&x[(size_t)tok * D_MODEL + t * 4];
  ushort4 o;
  o.x = f2bf(v.x); o.y = f2bf(v.y); o.z = f2bf(v.z); o.w = f2bf(v.w);
  *(ushort4*)&Xd[(size_t)r * D_MODEL + t * 4] = o;
}

// ---------------------------------------------------------------------------
// FFN pass 1 (fused gate+value): H = silu(Xd @ w1) * (Xd @ w2), bf16 out.
// Known-good R2/R7 structure: 128x128 tile, BK=64, 4 waves (2x2),
// 16x16x32 bf16 MFMA, global_load_lds staging, XOR chunk swizzle
// (read slot = chunk ^ (row&7), pre-swizzled global source; rule 21).
// __launch_bounds__(256,2): 2 blocks/CU is OPTIMAL — (256,3) tried in R9:
// L2 write-coalescing breaks (WRITE_SIZE 131->850 MB, +63% time). Keep 2.
// ---------------------------------------------------------------------------
__global__ __launch_bounds__(256, 2) void k_ffn1(const u16* __restrict__ Xd,
                                                 const u16* __restrict__ W1t,
                                                 const u16* __restrict__ W2t,
                                                 u16* __restrict__ H,
                                                 const int* __restrict__ info) {
  const int e = blockIdx.z;
  const int count = info[e];
  const int row0 = blockIdx.y * 128;
  if (row0 >= count) return;
  const int start = info[N_EXPERTS + e];
  const int col0 = blockIdx.x * 128;

  __shared__ u16 lsA[128 * 64];
  __shared__ u16 lsB1[128 * 64];
  __shared__ u16 lsB2[128 * 64];

  const int t = threadIdx.x, lane = t & 63, wid = t >> 6;
  const int wr = wid >> 1, wc = wid & 1;

  const u16* gA  = Xd  + (size_t)(start + row0) * D_MODEL;
  const u16* gB1 = W1t + (size_t)e * D_FF * D_MODEL + (size_t)col0 * D_MODEL;
  const u16* gB2 = W2t + (size_t)e * D_FF * D_MODEL + (size_t)col0 * D_MODEL;

  f32x4 accG[4][4] = {};
  f32x4 accV[4][4] = {};

  const int srow = wid * 8 + (lane >> 3);                       // + i*32
  const int skk  = (((lane & 7) ^ ((lane >> 3) & 7)) * 8);
  const int rk0 = (((0 * 4 + (lane >> 4)) ^ (lane & 7)) * 8);   // kk=0
  const int rk1 = (((1 * 4 + (lane >> 4)) ^ (lane & 7)) * 8);   // kk=1

  for (int k0 = 0; k0 < D_MODEL; k0 += 64) {
    __syncthreads();
    #pragma unroll
    for (int i = 0; i < 4; ++i) {
      int r = i * 32 + srow;
      int lbase = (i * 32 + wid * 8) * 64;
      gld_lds16(gA  + (size_t)r * D_MODEL + k0 + skk, &lsA[lbase]);
      gld_lds16(gB1 + (size_t)r * D_MODEL + k0 + skk, &lsB1[lbase]);
      gld_lds16(gB2 + (size_t)r * D_MODEL + k0 + skk, &lsB2[lbase]);
    }
    __syncthreads();   // drains vmcnt -> tiles ready
    #pragma unroll
    for (int kk = 0; kk < 2; ++kk) {
      const int rk = kk ? rk1 : rk0;
      bf16x8 a[4];
      #pragma unroll
      for (int m = 0; m < 4; ++m)
        a[m] = *(const bf16x8*)&lsA[(wr * 64 + m * 16 + (lane & 15)) * 64 + rk];
      #pragma unroll
      for (int n = 0; n < 4; ++n) {
        bf16x8 b1 = *(const bf16x8*)&lsB1[(wc * 64 + n * 16 + (lane & 15)) * 64 + rk];
        bf16x8 b2 = *(const bf16x8*)&lsB2[(wc * 64 + n * 16 + (lane & 15)) * 64 + rk];
        #pragma unroll
        for (int m = 0; m < 4; ++m) {
          accG[m][n] = __builtin_amdgcn_mfma_f32_16x16x32_bf16(a[m], b1, accG[m][n], 0, 0, 0);
          accV[m][n] = __builtin_amdgcn_mfma_f32_16x16x32_bf16(a[m], b2, accV[m][n], 0, 0, 0);
        }
      }
    }
  }

  const int rmax = count - row0;
  const size_t hbase = (size_t)(start + row0);
  #pragma unroll
  for (int m = 0; m < 4; ++m) {
    #pragma unroll
    for (int j = 0; j < 4; ++j) {
      int rit = wr * 64 + m * 16 + (lane >> 4) * 4 + j;  // D: row=(lane>>4)*4+reg
      if (rit < rmax) {
        #pragma unroll
        for (int n = 0; n < 4; ++n) {
          float g = accG[m][n][j];
          float v = accV[m][n][j];
          float h = g * v / (1.0f + __expf(-g));   // silu(g)*v
          H[(hbase + rit) * D_FF + col0 + wc * 64 + n * 16 + (lane & 15)] = f2bf(h);
        }
      }
    }
  }
}

// ---------------------------------------------------------------------------
// FFN pass 2: Y = H @ w3 (B^T layout), bf16 out. Known-good R2/R7 structure:
// 128x128 tile, BK=64, 4 waves, 32 KiB LDS (~4 blocks/CU residency).
// ---------------------------------------------------------------------------
__global__ __launch_bounds__(256) void k_ffn2(const u16* __restrict__ Hbuf,
                                              const u16* __restrict__ W3t,
                                              u16* __restrict__ Y,
                                              const int* __restrict__ info) {
  const int e = blockIdx.z;
  const int count = info[e];
  const int row0 = blockIdx.y * 128;
  if (row0 >= count) return;
  const int start = info[N_EXPERTS + e];
  const int col0 = blockIdx.x * 128;

  __shared__ u16 lsA[128 * 64];
  __shared__ u16 lsB[128 * 64];

  const int t = threadIdx.x, lane = t & 63, wid = t >> 6;
  const int wr = wid >> 1, wc = wid & 1;

  const u16* gA = Hbuf + (size_t)(start + row0) * D_FF;
  const u16* gB = W3t + (size_t)e * D_MODEL * D_FF + (size_t)col0 * D_FF;

  f32x4 acc[4][4] = {};

  const int srow = wid * 8 + (lane >> 3);
  const int skk  = (((lane & 7) ^ ((lane >> 3) & 7)) * 8);
  const int rk0 = (((0 * 4 + (lane >> 4)) ^ (lane & 7)) * 8);
  const int rk1 = (((1 * 4 + (lane >> 4)) ^ (lane & 7)) * 8);

  for (int k0 = 0; k0 < D_FF; k0 += 64) {
    __syncthreads();
    #pragma unroll
    for (int i = 0; i < 4; ++i) {
      int r = i * 32 + srow;
      int lbase = (i * 32 + wid * 8) * 64;
      gld_lds16(gA + (size_t)r * D_FF + k0 + skk, &lsA[lbase]);
      gld_lds16(gB + (size_t)r * D_FF + k0 + skk, &lsB[lbase]);
    }
    __syncthreads();
    #pragma unroll
    for (int kk = 0; kk < 2; ++kk) {
      const int rk = kk ? rk1 : rk0;
      bf16x8 a[4];
      #pragma unroll
      for (int m = 0; m < 4; ++m)
        a[m] = *(const bf16x8*)&lsA[(wr * 64 + m * 16 + (lane & 15)) * 64 + rk];
      #pragma unroll
      for (int n = 0; n < 4; ++n) {
        bf16x8 b = *(const bf16x8*)&lsB[(wc * 64 + n * 16 + (lane & 15)) * 64 + rk];
        #pragma unroll
        for (int m = 0; m < 4; ++m)
          acc[m][n] = __builtin_amdgcn_mfma_f32_16x16x32_bf16(a[m], b, acc[m][n], 0, 0, 0);
      }
    }
  }

  const int rmax = count - row0;
  const size_t ybase = (size_t)(start + row0);
  #pragma unroll
  for (int m = 0; m < 4; ++m) {
    #pragma unroll
    for (int j = 0; j < 4; ++j) {
      int rit = wr * 64 + m * 16 + (lane >> 4) * 4 + j;
      if (rit < rmax) {
        #pragma unroll
        for (int n = 0; n < 4; ++n)
          Y[(ybase + rit) * D_MODEL + col0 + wc * 64 + n * 16 + (lane & 15)] = f2bf(acc[m][n][j]);
      }
    }
  }
}

// ---------------------------------------------------------------------------
// Combine: out[t] = sum_k w[t,k] * Y[row(t,k)]   (deterministic k order)
// ---------------------------------------------------------------------------
__global__ __launch_bounds__(256) void k_combine(const u16* __restrict__ Y,
                                                 const int* __restrict__ row_of_slot,
                                                 const float* __restrict__ ew,
                                                 float* __restrict__ out) {
  const int tok = blockIdx.x;
  const int c = threadIdx.x * 4;
  const int r0 = row_of_slot[tok * 2 + 0];
  const int r1 = row_of_slot[tok * 2 + 1];
  const float w0 = ew[tok * 2 + 0];
  const float w1 = ew[tok * 2 + 1];
  float a0 = 0.f, a1 = 0.f, a2 = 0.f, a3 = 0.f;
  if (r0 >= 0) {
    ushort4 y = *(const ushort4*)&Y[(size_t)r0 * D_MODEL + c];
    a0 = w0 * bf2f(y.x); a1 = w0 * bf2f(y.y); a2 = w0 * bf2f(y.z); a3 = w0 * bf2f(y.w);
  }
  if (r1 >= 0) {
    ushort4 y = *(const ushort4*)&Y[(size_t)r1 * D_MODEL + c];
    a0 += w1 * bf2f(y.x); a1 += w1 * bf2f(y.y); a2 += w1 * bf2f(y.z); a3 += w1 * bf2f(y.w);
  }
  float4 o; o.x = a0; o.y = a1; o.z = a2; o.w = a3;
  *(float4*)&out[(size_t)tok * D_MODEL + c] = o;
}

// ---------------------------------------------------------------------------
extern "C" void kernel_launch(void* const* d_in, const int* in_sizes, int n_in,
                              void* d_out, int out_size, void* d_ws, size_t ws_size,
                              hipStream_t stream) {
  const float* x  = (const float*)d_in[0];
  const int*   ei = (const int*)d_in[1];
  const float* ew = (const float*)d_in[2];
  const float* w1 = (const float*)d_in[3];
  const float* w2 = (const float*)d_in[4];
  const float* w3 = (const float*)d_in[5];
  float* out = (float*)d_out;

  char* ws = (char*)d_ws;
  size_t off = 0;
  auto alloc = [&](size_t b) { char* p = ws + off; off += (b + 255) & ~(size_t)255; return p; };
  int* info        = (int*)alloc(256);
  int* row_of_slot = (int*)alloc(sizeof(int) * TOTAL_SLOTS);
  int* tok_of_row  = (int*)alloc(sizeof(int) * ROWS_PAD);
  u16* Xd  = (u16*)alloc((size_t)2 * ROWS_PAD * D_MODEL);
  u16* W1t = (u16*)alloc((size_t)2 * N_EXPERTS * D_FF * D_MODEL);
  u16* W2t = (u16*)alloc((size_t)2 * N_EXPERTS * D_FF * D_MODEL);
  u16* W3t = (u16*)alloc((size_t)2 * N_EXPERTS * D_FF * D_MODEL);
  u16* H   = (u16*)alloc((size_t)2 * ROWS_PAD * D_FF);
  u16* Y   = (u16*)alloc((size_t)2 * ROWS_PAD * D_MODEL);

  k_route<<<1, RT_THREADS, 0, stream>>>(ei, info, row_of_slot, tok_of_row);
  k_transpose_all<<<dim3(64, 16, 24), 256, 0, stream>>>(w1, w2, w3, W1t, W2t, W3t);
  k_dispatch<<<ROWS_PAD, 256, 0, stream>>>(x, tok_of_row, info, Xd);
  k_ffn1<<<dim3(D_FF / 128, CAP / 128, N_EXPERTS), 256, 0, stream>>>(Xd, W1t, W2t, H, info);
  k_ffn2<<<dim3(D_MODEL / 128, CAP / 128, N_EXPERTS), 256, 0, stream>>>(H, W3t, Y, info);
  k_combine<<<N_TOKENS, 256, 0, stream>>>(Y, row_of_slot, ew, out);
}